// Round 1
// baseline (175.682 us; speedup 1.0000x reference)
//
#include <hip/hip_runtime.h>
#include <math.h>

// Problem constants (B, C, H, W) = (32, 10, 192, 320), fp32.
constexpr int B_ = 32, C_ = 10, H_ = 192, W_ = 320;
constexpr int HW_  = H_ * W_;        // 61440 (divisible by 4)
constexpr int CHW_ = C_ * HW_;       // 614400
constexpr int NPTS = B_ * HW_;       // 1966080 spatial points
constexpr int PPT  = 4;              // points per thread (float4 per channel)
constexpr int TPB  = 128;            // 2 waves/block, fine-grained tail balance
constexpr int NTHR = NPTS / PPT;     // 491520 threads
constexpr int NBLK = NTHR / TPB;     // 3840 blocks, exact cover

// Partial-sum slots, ws[slot * NBLK + blk]. Final weights folded per-thread:
// 0: nv      (sum of valid mask)
// 1: num_pos
// 2: sum pos*(g0-r0)^2*log(safe+EPS)            (pos_term = -this)
// 3: sum neg*r0^2*log(1+EPS-safe)*(1-g0)^4      (neg_term = -this)
// 4: P  = 0.5*s_pos + 0.5*s_const + 0.1*s_h     (-> P/nv)
// 5: V1 = 0.05*s_len1 + 0.5*s_trig1             (-> V1/nv)
// 6: V2 = 0.05*s_len2 + 0.5*s_trig2             (-> V2/nv)
// loss = focal + (P + min(V1,V2)) / nv
#define NACC 7

__device__ __forceinline__ float sl1f(float d) {
    float ad = fabsf(d);
    return ad < 1.0f ? 0.5f * d * d : ad - 0.5f;
}

// Round-4 evidence: prior kernel was MLP-bound, NOT bandwidth-bound
// (L3-warm pass had FETCH ~0.86 MB yet identical 57 us; VGPR_Count=32 means
// compiler sank the loads -> only ~2 loads in flight/wave). Fix: float4 per
// channel (16 B/lane) and a sched_barrier(0) fence after all 20 loads so the
// full load epoch (~80 data VGPRs, 20 dwordx4 in flight) cannot be sunk.
__global__ __launch_bounds__(TPB) void loss_main(
    const float* __restrict__ re, const float* __restrict__ gt,
    float* __restrict__ ws)
{
    const int tid = blockIdx.x * TPB + threadIdx.x;
    const int p = tid * PPT;
    const int b = p / HW_;           // PPT divides HW_: no b-boundary crossing
    const int s = p - b * HW_;
    const float* rp = re + (size_t)b * CHW_ + s;
    const float* gp = gt + (size_t)b * CHW_ + s;

    // One load epoch: 20 independent coalesced dwordx4 loads, all issued
    // before any compute (fence below makes this non-negotiable).
    float4 R[10], G[10];
#pragma unroll
    for (int c = 0; c < 10; ++c) {
        R[c] = *(const float4*)(rp + c * HW_);
        G[c] = *(const float4*)(gp + c * HW_);
    }
    __builtin_amdgcn_sched_barrier(0);   // loads may not sink past this point

    float acc[NACC];
#pragma unroll
    for (int i = 0; i < NACC; ++i) acc[i] = 0.0f;

#pragma unroll
    for (int j = 0; j < PPT; ++j) {
        #define RC(c) (((const float*)&R[c])[j])
        #define GC(c) (((const float*)&G[c])[j])
        const float g = GC(0), r = RC(0);
        const float m = (g == 1.0f) ? 1.0f : 0.0f;
        acc[0] += m;
        const float pos = (g >= 0.1f) ? 1.0f : 0.0f;
        const float neg = ((g >= 0.0f) && (g < 0.1f)) ? 1.0f : 0.0f;
        acc[1] += pos;
        const float safe = fminf(fmaxf(r, 1e-6f), 1.0f - 1e-6f);
        // pos and neg are mutually exclusive -> a single logf with a selected
        // argument. Dead branch multiplies finite log by exactly 0.0f.
        const float larg = (pos != 0.0f) ? (safe + 6e-8f)
                                         : (1.0f + 6e-8f - safe);
        const float lg = logf(larg);
        const float d0 = g - r;
        acc[2] += pos * (d0 * d0) * lg;
        const float omg = 1.0f - g;
        const float omg2 = omg * omg;
        acc[3] += neg * (r * r) * (omg2 * omg2) * lg;

        const float r1 = RC(1), r2 = RC(2), r3 = RC(3), r4v = RC(4);
        const float r5 = RC(5), r6 = RC(6), r7 = RC(7), r8 = RC(8), r9 = RC(9);
        const float g1 = GC(1), g2 = GC(2), g3 = GC(3), g4v = GC(4);
        const float g5 = GC(5), g6 = GC(6), g7 = GC(7), g8 = GC(8), g9 = GC(9);

        // P: pos(0.5) + const(0.5) + height(0.1), all later /nv
        const float sp = sl1f(r1 - g1) + sl1f(r2 - g2);
        const float c1 = 1.0f - r5 * r5 - r4v * r4v;
        const float c2 = 1.0f - r8 * r8 - r7 * r7;
        const float sc = c1 * c1 + c2 * c2;
        const float sh = sl1f(r9 - g9);
        acc[4] += m * (0.5f * sp + 0.5f * sc + 0.1f * sh);

        // V1: 0.05*len1 + 0.5*trig1
        const float d44 = r4v - g4v, d77 = r7 - g7;
        const float d55 = r5 - g5,  d88 = r8 - g8;
        const float t1 = d44 * d44 + d77 * d77 + d55 * d55 + d88 * d88;
        const float l1 = sl1f(r3 - g3) + sl1f(r6 - g6);
        acc[5] += m * (0.05f * l1 + 0.5f * t1);

        // V2: 0.05*len2 + 0.5*trig2
        const float d47 = r4v - g7, d74 = r7 - g4v;
        const float d58 = r5 - g8,  d85 = r8 - g5;
        const float t2 = d47 * d47 + d74 * d74 + d58 * d58 + d85 * d85;
        const float l2 = sl1f(r3 - g6) + sl1f(r6 - g3);
        acc[6] += m * (0.05f * l2 + 0.5f * t2);
        #undef RC
        #undef GC
    }

    // block reduction: wave shuffle (64 lanes) -> LDS (2 waves) -> plain store
    __shared__ float smem[NACC][2];
    const int lane = threadIdx.x & 63;
    const int wid  = threadIdx.x >> 6;
#pragma unroll
    for (int i = 0; i < NACC; ++i) {
        float v = acc[i];
#pragma unroll
        for (int off = 32; off > 0; off >>= 1) v += __shfl_down(v, off, 64);
        if (lane == 0) smem[i][wid] = v;
    }
    __syncthreads();
    if (threadIdx.x < NACC) {
        const int i = threadIdx.x;
        ws[i * NBLK + blockIdx.x] = smem[i][0] + smem[i][1];
    }
}

// One block, 1024 threads: all 7*3840 partials in one parallel load epoch.
__global__ __launch_bounds__(1024) void loss_reduce(
    const float* __restrict__ ws, float* __restrict__ out)
{
    float acc[NACC];
#pragma unroll
    for (int i = 0; i < NACC; ++i) acc[i] = 0.0f;

#pragma unroll
    for (int k = 0; k < 4; ++k) {
        const int idx = threadIdx.x + k * 1024;
        if (idx < NBLK) {
#pragma unroll
            for (int i = 0; i < NACC; ++i)
                acc[i] += ws[i * NBLK + idx];
        }
    }

    __shared__ float smem[NACC][16];
    const int lane = threadIdx.x & 63;
    const int wid  = threadIdx.x >> 6;
#pragma unroll
    for (int i = 0; i < NACC; ++i) {
        float v = acc[i];
#pragma unroll
        for (int off = 32; off > 0; off >>= 1) v += __shfl_down(v, off, 64);
        if (lane == 0) smem[i][wid] = v;
    }
    __syncthreads();

    if (threadIdx.x == 0) {
        float slot[NACC];
#pragma unroll
        for (int i = 0; i < NACC; ++i) {
            float v = 0.0f;
#pragma unroll
            for (int w = 0; w < 16; ++w) v += smem[i][w];
            slot[i] = v;
        }
        const float nv    = slot[0];
        const float npos  = slot[1];
        const float pterm = -slot[2];
        const float nterm = -slot[3];
        const float focal = (npos == 0.0f) ? nterm : (pterm + nterm) / npos;
        out[0] = focal + (slot[4] + fminf(slot[5], slot[6])) / nv;
    }
}

extern "C" void kernel_launch(void* const* d_in, const int* in_sizes, int n_in,
                              void* d_out, int out_size, void* d_ws, size_t ws_size,
                              hipStream_t stream)
{
    const float* re = (const float*)d_in[0];
    const float* gt = (const float*)d_in[1];
    float* ws  = (float*)d_ws;
    float* out = (float*)d_out;

    loss_main<<<NBLK, TPB, 0, stream>>>(re, gt, ws);
    loss_reduce<<<1, 1024, 0, stream>>>(ws, out);
}

// Round 2
// 175.427 us; speedup vs baseline: 1.0015x; 1.0015x over previous
//
#include <hip/hip_runtime.h>
#include <math.h>

// Problem constants (B, C, H, W) = (32, 10, 192, 320), fp32.
constexpr int B_ = 32, C_ = 10, H_ = 192, W_ = 320;
constexpr int HW_  = H_ * W_;        // 61440 (divisible by 4)
constexpr int CHW_ = C_ * HW_;       // 614400
constexpr int NPTS = B_ * HW_;       // 1966080 spatial points
constexpr int PPT  = 4;              // points per thread (float4 per channel)
constexpr int TPB  = 128;            // 2 waves/block; 3840 blocks = 15/CU exact
constexpr int NTHR = NPTS / PPT;     // 491520 threads
constexpr int NBLK = NTHR / TPB;     // 3840 blocks, exact cover

// Partial-sum slots, ws[slot * NBLK + blk]. Final weights folded per-thread:
// 0: nv      (sum of valid mask)
// 1: num_pos
// 2: sum pos*(g0-r0)^2*log(safe+EPS)            (pos_term = -this)
// 3: sum neg*r0^2*log(1+EPS-safe)*(1-g0)^4      (neg_term = -this)
// 4: P  = 0.5*s_pos + 0.5*s_const + 0.1*s_h     (-> P/nv)
// 5: V1 = 0.05*s_len1 + 0.5*s_trig1             (-> V1/nv)
// 6: V2 = 0.05*s_len2 + 0.5*s_trig2             (-> V2/nv)
// loss = focal + (P + min(V1,V2)) / nv
#define NACC 7

__device__ __forceinline__ float sl1f(float d) {
    float ad = fabsf(d);
    return ad < 1.0f ? 0.5f * d * d : ad - 0.5f;
}

// Round-5 evidence: sched_barrier(0) did NOT materialize the load epoch
// (VGPR_Count=52 < 80 needed for 20 live dwordx4 results -> compiler still
// interleaved load->use batches; ~2-3 loads in flight/wave; 2.66 TB/s
// effective, 42% of achievable). Fix: empty volatile asm with "+v" ties on
// every loaded component, one asm per channel, AFTER all 20 loads. Volatile
// asms are ordered against each other and tie the load results, so all 80
// floats are provably live at the last asm -> the full 20-load epoch with
// telescoped vmcnt waits is forced. Confirmation signal: VGPR_Count ~100+.
__global__ __launch_bounds__(TPB) void loss_main(
    const float* __restrict__ re, const float* __restrict__ gt,
    float* __restrict__ ws)
{
    const int tid = blockIdx.x * TPB + threadIdx.x;
    const int p = tid * PPT;
    const int b = p / HW_;           // PPT divides HW_: no b-boundary crossing
    const int s = p - b * HW_;
    const float* rp = re + (size_t)b * CHW_ + s;
    const float* gp = gt + (size_t)b * CHW_ + s;

    // One load epoch: 20 independent coalesced dwordx4 loads.
    float4 R[10], G[10];
#pragma unroll
    for (int c = 0; c < 10; ++c) {
        R[c] = *(const float4*)(rp + c * HW_);
        G[c] = *(const float4*)(gp + c * HW_);
    }
    // Force the epoch: all 80 components live here, loads may not sink.
#pragma unroll
    for (int c = 0; c < 10; ++c) {
        asm volatile("" : "+v"(R[c].x), "+v"(R[c].y), "+v"(R[c].z), "+v"(R[c].w),
                          "+v"(G[c].x), "+v"(G[c].y), "+v"(G[c].z), "+v"(G[c].w));
    }
    __builtin_amdgcn_sched_barrier(0);

    float acc[NACC];
#pragma unroll
    for (int i = 0; i < NACC; ++i) acc[i] = 0.0f;

#pragma unroll
    for (int j = 0; j < PPT; ++j) {
        #define RC(c) (((const float*)&R[c])[j])
        #define GC(c) (((const float*)&G[c])[j])
        const float g = GC(0), r = RC(0);
        const float m = (g == 1.0f) ? 1.0f : 0.0f;
        acc[0] += m;
        const float pos = (g >= 0.1f) ? 1.0f : 0.0f;
        const float neg = ((g >= 0.0f) && (g < 0.1f)) ? 1.0f : 0.0f;
        acc[1] += pos;
        const float safe = fminf(fmaxf(r, 1e-6f), 1.0f - 1e-6f);
        // pos and neg are mutually exclusive -> a single logf with a selected
        // argument. Dead branch multiplies finite log by exactly 0.0f.
        const float larg = (pos != 0.0f) ? (safe + 6e-8f)
                                         : (1.0f + 6e-8f - safe);
        const float lg = logf(larg);
        const float d0 = g - r;
        acc[2] += pos * (d0 * d0) * lg;
        const float omg = 1.0f - g;
        const float omg2 = omg * omg;
        acc[3] += neg * (r * r) * (omg2 * omg2) * lg;

        const float r1 = RC(1), r2 = RC(2), r3 = RC(3), r4v = RC(4);
        const float r5 = RC(5), r6 = RC(6), r7 = RC(7), r8 = RC(8), r9 = RC(9);
        const float g1 = GC(1), g2 = GC(2), g3 = GC(3), g4v = GC(4);
        const float g5 = GC(5), g6 = GC(6), g7 = GC(7), g8 = GC(8), g9 = GC(9);

        // P: pos(0.5) + const(0.5) + height(0.1), all later /nv
        const float sp = sl1f(r1 - g1) + sl1f(r2 - g2);
        const float c1 = 1.0f - r5 * r5 - r4v * r4v;
        const float c2 = 1.0f - r8 * r8 - r7 * r7;
        const float sc = c1 * c1 + c2 * c2;
        const float sh = sl1f(r9 - g9);
        acc[4] += m * (0.5f * sp + 0.5f * sc + 0.1f * sh);

        // V1: 0.05*len1 + 0.5*trig1
        const float d44 = r4v - g4v, d77 = r7 - g7;
        const float d55 = r5 - g5,  d88 = r8 - g8;
        const float t1 = d44 * d44 + d77 * d77 + d55 * d55 + d88 * d88;
        const float l1 = sl1f(r3 - g3) + sl1f(r6 - g6);
        acc[5] += m * (0.05f * l1 + 0.5f * t1);

        // V2: 0.05*len2 + 0.5*trig2
        const float d47 = r4v - g7, d74 = r7 - g4v;
        const float d58 = r5 - g8,  d85 = r8 - g5;
        const float t2 = d47 * d47 + d74 * d74 + d58 * d58 + d85 * d85;
        const float l2 = sl1f(r3 - g6) + sl1f(r6 - g3);
        acc[6] += m * (0.05f * l2 + 0.5f * t2);
        #undef RC
        #undef GC
    }

    // block reduction: wave shuffle (64 lanes) -> LDS (2 waves) -> plain store
    __shared__ float smem[NACC][2];
    const int lane = threadIdx.x & 63;
    const int wid  = threadIdx.x >> 6;
#pragma unroll
    for (int i = 0; i < NACC; ++i) {
        float v = acc[i];
#pragma unroll
        for (int off = 32; off > 0; off >>= 1) v += __shfl_down(v, off, 64);
        if (lane == 0) smem[i][wid] = v;
    }
    __syncthreads();
    if (threadIdx.x < NACC) {
        const int i = threadIdx.x;
        ws[i * NBLK + blockIdx.x] = smem[i][0] + smem[i][1];
    }
}

// One block, 960 threads: 960*4 = 3840 exact -> guard-free, all 28 loads per
// thread independent, single load epoch.
__global__ __launch_bounds__(960) void loss_reduce(
    const float* __restrict__ ws, float* __restrict__ out)
{
    float acc[NACC];
#pragma unroll
    for (int i = 0; i < NACC; ++i) acc[i] = 0.0f;

#pragma unroll
    for (int k = 0; k < 4; ++k) {
        const int idx = threadIdx.x + k * 960;
#pragma unroll
        for (int i = 0; i < NACC; ++i)
            acc[i] += ws[i * NBLK + idx];
    }

    __shared__ float smem[NACC][15];
    const int lane = threadIdx.x & 63;
    const int wid  = threadIdx.x >> 6;
#pragma unroll
    for (int i = 0; i < NACC; ++i) {
        float v = acc[i];
#pragma unroll
        for (int off = 32; off > 0; off >>= 1) v += __shfl_down(v, off, 64);
        if (lane == 0) smem[i][wid] = v;
    }
    __syncthreads();

    if (threadIdx.x == 0) {
        float slot[NACC];
#pragma unroll
        for (int i = 0; i < NACC; ++i) {
            float v = 0.0f;
#pragma unroll
            for (int w = 0; w < 15; ++w) v += smem[i][w];
            slot[i] = v;
        }
        const float nv    = slot[0];
        const float npos  = slot[1];
        const float pterm = -slot[2];
        const float nterm = -slot[3];
        const float focal = (npos == 0.0f) ? nterm : (pterm + nterm) / npos;
        out[0] = focal + (slot[4] + fminf(slot[5], slot[6])) / nv;
    }
}

extern "C" void kernel_launch(void* const* d_in, const int* in_sizes, int n_in,
                              void* d_out, int out_size, void* d_ws, size_t ws_size,
                              hipStream_t stream)
{
    const float* re = (const float*)d_in[0];
    const float* gt = (const float*)d_in[1];
    float* ws  = (float*)d_ws;
    float* out = (float*)d_out;

    loss_main<<<NBLK, TPB, 0, stream>>>(re, gt, ws);
    loss_reduce<<<1, 960, 0, stream>>>(ws, out);
}

// Round 3
// 175.365 us; speedup vs baseline: 1.0018x; 1.0004x over previous
//
#include <hip/hip_runtime.h>
#include <math.h>

// Problem constants (B, C, H, W) = (32, 10, 192, 320), fp32.
constexpr int B_ = 32, C_ = 10, H_ = 192, W_ = 320;
constexpr int HW_  = H_ * W_;        // 61440 (divisible by 512 -> no b-crossing per block)
constexpr int CHW_ = C_ * HW_;       // 614400
constexpr int NPTS = B_ * HW_;       // 1966080 spatial points
constexpr int PPT  = 4;              // points per thread (16 B/lane)
constexpr int TPB  = 128;            // 2 waves/block
constexpr int NTHR = NPTS / PPT;     // 491520 threads
constexpr int NBLK = NTHR / TPB;     // 3840 blocks, exact cover, 15/CU

// Partial-sum slots, ws[slot * NBLK + blk]. Final weights folded per-thread:
// 0: nv  1: num_pos
// 2: sum pos*(g0-r0)^2*log(safe+EPS)            (pos_term = -this)
// 3: sum neg*r0^2*log(1+EPS-safe)*(1-g0)^4      (neg_term = -this)
// 4: P  = 0.5*s_pos + 0.5*s_const + 0.1*s_h     (-> P/nv)
// 5: V1 = 0.05*s_len1 + 0.5*s_trig1             (-> V1/nv)
// 6: V2 = 0.05*s_len2 + 0.5*s_trig2             (-> V2/nv)
// loss = focal + (P + min(V1,V2)) / nv
#define NACC 7

__device__ __forceinline__ float sl1f(float d) {
    float ad = fabsf(d);
    return ad < 1.0f ? 0.5f * d * d : ad - 0.5f;
}

// Round-6 evidence: VGPR=52 again -> per-channel volatile asms MANDATED
// load->wait->asm serialization (each load only had to precede its own asm):
// ~1 load in flight/wave. Model: waves/CU x 1KB / ~2300cy loaded-latency
// = 4.4 B/cyc/CU == measured 4.33. Round-0 config lands on the same curve
// (18 waves x 0.5KB). So the kernel has been MLP=1 all along.
// Fix: global_load_lds staging -- loads have NO VGPR result, so nothing
// forces a wait between issues. All 20 loads per wave go in flight, one
// s_waitcnt vmcnt(0), then ds_read_b128 the data back. LDS 40KB/block ->
// 4 blocks/CU -> 160KB in flight per CU (need ~25KB for 6.3 TB/s @ 2300cy).
__device__ __forceinline__ void gload_lds16(const float* g, void* l) {
    __builtin_amdgcn_global_load_lds(
        (const __attribute__((address_space(1))) unsigned int*)g,
        (__attribute__((address_space(3))) unsigned int*)l, 16, 0, 0);
}

__global__ __launch_bounds__(TPB) void loss_main(
    const float* __restrict__ re, const float* __restrict__ gt,
    float* __restrict__ ws)
{
    // [wave][stream (R,G interleaved)][lane][4 floats] = 40 KiB
    __shared__ float lds[2][20][64][4];

    const int tid = blockIdx.x * TPB + threadIdx.x;
    const int p = tid * PPT;
    const int b = p / HW_;           // no b-crossing inside a block (512 | HW_)
    const int s = p - b * HW_;
    const float* rp = re + (size_t)b * CHW_ + s;
    const float* gp = gt + (size_t)b * CHW_ + s;
    const int lane = threadIdx.x & 63;
    const int wid  = threadIdx.x >> 6;

    // 20 direct-to-LDS loads per wave, all in flight simultaneously.
    // Global src is per-lane (lane-contiguous 16B => 1KB/instr coalesced);
    // LDS dest is wave-uniform base, HW scatters at base + lane*16.
#pragma unroll
    for (int c = 0; c < 10; ++c) {
        gload_lds16(rp + c * HW_, &lds[wid][2 * c    ][0][0]);
        gload_lds16(gp + c * HW_, &lds[wid][2 * c + 1][0][0]);
    }
    // One wait for the whole epoch (vmcnt counts global_load_lds).
    asm volatile("s_waitcnt vmcnt(0)" ::: "memory");

    // Read back own lane's data: ds_read_b128, lane-contiguous, conflict-free.
    float4 R[10], G[10];
#pragma unroll
    for (int c = 0; c < 10; ++c) {
        R[c] = *(const float4*)&lds[wid][2 * c    ][lane][0];
        G[c] = *(const float4*)&lds[wid][2 * c + 1][lane][0];
    }

    float acc[NACC];
#pragma unroll
    for (int i = 0; i < NACC; ++i) acc[i] = 0.0f;

#pragma unroll
    for (int j = 0; j < PPT; ++j) {
        #define RC(c) (((const float*)&R[c])[j])
        #define GC(c) (((const float*)&G[c])[j])
        const float g = GC(0), r = RC(0);
        const float m = (g == 1.0f) ? 1.0f : 0.0f;
        acc[0] += m;
        const float pos = (g >= 0.1f) ? 1.0f : 0.0f;
        const float neg = ((g >= 0.0f) && (g < 0.1f)) ? 1.0f : 0.0f;
        acc[1] += pos;
        const float safe = fminf(fmaxf(r, 1e-6f), 1.0f - 1e-6f);
        // pos and neg mutually exclusive -> one logf with selected argument.
        const float larg = (pos != 0.0f) ? (safe + 6e-8f)
                                         : (1.0f + 6e-8f - safe);
        const float lg = logf(larg);
        const float d0 = g - r;
        acc[2] += pos * (d0 * d0) * lg;
        const float omg = 1.0f - g;
        const float omg2 = omg * omg;
        acc[3] += neg * (r * r) * (omg2 * omg2) * lg;

        const float r1 = RC(1), r2 = RC(2), r3 = RC(3), r4v = RC(4);
        const float r5 = RC(5), r6 = RC(6), r7 = RC(7), r8 = RC(8), r9 = RC(9);
        const float g1 = GC(1), g2 = GC(2), g3 = GC(3), g4v = GC(4);
        const float g5 = GC(5), g6 = GC(6), g7 = GC(7), g8 = GC(8), g9 = GC(9);

        // P: pos(0.5) + const(0.5) + height(0.1), all later /nv
        const float sp = sl1f(r1 - g1) + sl1f(r2 - g2);
        const float c1 = 1.0f - r5 * r5 - r4v * r4v;
        const float c2 = 1.0f - r8 * r8 - r7 * r7;
        const float sc = c1 * c1 + c2 * c2;
        const float sh = sl1f(r9 - g9);
        acc[4] += m * (0.5f * sp + 0.5f * sc + 0.1f * sh);

        // V1: 0.05*len1 + 0.5*trig1
        const float d44 = r4v - g4v, d77 = r7 - g7;
        const float d55 = r5 - g5,  d88 = r8 - g8;
        const float t1 = d44 * d44 + d77 * d77 + d55 * d55 + d88 * d88;
        const float l1 = sl1f(r3 - g3) + sl1f(r6 - g6);
        acc[5] += m * (0.05f * l1 + 0.5f * t1);

        // V2: 0.05*len2 + 0.5*trig2
        const float d47 = r4v - g7, d74 = r7 - g4v;
        const float d58 = r5 - g8,  d85 = r8 - g5;
        const float t2 = d47 * d47 + d74 * d74 + d58 * d58 + d85 * d85;
        const float l2 = sl1f(r3 - g6) + sl1f(r6 - g3);
        acc[6] += m * (0.05f * l2 + 0.5f * t2);
        #undef RC
        #undef GC
    }

    // block reduction: wave shuffle (64 lanes) -> LDS (2 waves) -> plain store
    __shared__ float smem[NACC][2];
#pragma unroll
    for (int i = 0; i < NACC; ++i) {
        float v = acc[i];
#pragma unroll
        for (int off = 32; off > 0; off >>= 1) v += __shfl_down(v, off, 64);
        if (lane == 0) smem[i][wid] = v;
    }
    __syncthreads();
    if (threadIdx.x < NACC) {
        const int i = threadIdx.x;
        ws[i * NBLK + blockIdx.x] = smem[i][0] + smem[i][1];
    }
}

// One block, 960 threads: 960*4 = 3840 exact -> guard-free, all 28 loads per
// thread independent, single load epoch.
__global__ __launch_bounds__(960) void loss_reduce(
    const float* __restrict__ ws, float* __restrict__ out)
{
    float acc[NACC];
#pragma unroll
    for (int i = 0; i < NACC; ++i) acc[i] = 0.0f;

#pragma unroll
    for (int k = 0; k < 4; ++k) {
        const int idx = threadIdx.x + k * 960;
#pragma unroll
        for (int i = 0; i < NACC; ++i)
            acc[i] += ws[i * NBLK + idx];
    }

    __shared__ float smem[NACC][15];
    const int lane = threadIdx.x & 63;
    const int wid  = threadIdx.x >> 6;
#pragma unroll
    for (int i = 0; i < NACC; ++i) {
        float v = acc[i];
#pragma unroll
        for (int off = 32; off > 0; off >>= 1) v += __shfl_down(v, off, 64);
        if (lane == 0) smem[i][wid] = v;
    }
    __syncthreads();

    if (threadIdx.x == 0) {
        float slot[NACC];
#pragma unroll
        for (int i = 0; i < NACC; ++i) {
            float v = 0.0f;
#pragma unroll
            for (int w = 0; w < 15; ++w) v += smem[i][w];
            slot[i] = v;
        }
        const float nv    = slot[0];
        const float npos  = slot[1];
        const float pterm = -slot[2];
        const float nterm = -slot[3];
        const float focal = (npos == 0.0f) ? nterm : (pterm + nterm) / npos;
        out[0] = focal + (slot[4] + fminf(slot[5], slot[6])) / nv;
    }
}

extern "C" void kernel_launch(void* const* d_in, const int* in_sizes, int n_in,
                              void* d_out, int out_size, void* d_ws, size_t ws_size,
                              hipStream_t stream)
{
    const float* re = (const float*)d_in[0];
    const float* gt = (const float*)d_in[1];
    float* ws  = (float*)d_ws;
    float* out = (float*)d_out;

    loss_main<<<NBLK, TPB, 0, stream>>>(re, gt, ws);
    loss_reduce<<<1, 960, 0, stream>>>(ws, out);
}